// Round 4
// baseline (116.843 us; speedup 1.0000x reference)
//
#include <hip/hip_runtime.h>
#include <math.h>

#define FLT_BIG 3.0e38f

// Kernel A: per-ray min squared distance over M points.
// Block 256 = 8 ray-groups x 32 m-chunks. Each thread: 8 rays, M/32 points.
// LDS: M float4 (x,y,z, 0.5*|q|^2) = 64KB -> 2 blocks/CU.
// Per point per thread: 1 ds_read_b128 amortized over 8 rays (4 VALU/ray).
__global__ __launch_bounds__(256, 2) void chamfer_min_kernel(
    const float* __restrict__ cparam,   // B x 25
    const float* __restrict__ depth,    // B x N
    const float* __restrict__ pc,       // B x M x 3
    float* __restrict__ d0,             // B x N (clamped >= 0)
    int N, int M, int R)
{
    const int b   = blockIdx.y;
    const int tid = threadIdx.x;

    extern __shared__ float4 s4[];      // M entries

    const float* pcb = pc + (size_t)b * M * 3;
    for (int idx = tid; idx < M; idx += 256) {
        float x = pcb[idx * 3 + 0];
        float y = pcb[idx * 3 + 1];
        float z = pcb[idx * 3 + 2];
        s4[idx] = make_float4(x, y, z, 0.5f * (x * x + y * y + z * z));
    }
    __syncthreads();

    const float* cb = cparam + (size_t)b * 25;
    const float fx = cb[16], sk = cb[17], cx = cb[18];
    const float fy = cb[20], cy = cb[21];

    const int chunk = tid & 31;              // m-chunk 0..31
    const int grp   = tid >> 5;              // ray group 0..7
    const int nbase = blockIdx.x * 64 + grp * 8;

    float px[8], py[8], pz[8], e[8];
    #pragma unroll
    for (int r = 0; r < 8; r++) {
        const int n = nbase + r;
        const int i = n / R;
        const int j = n - i * R;
        const float x_cam = (j + 0.5f) / (float)R;
        const float y_cam = (i + 0.5f) / (float)R;
        const float x_lift = (x_cam - cx + cy * sk / fy - sk * y_cam / fy) / fx;
        const float y_lift = (y_cam - cy) / fy;
        const float dxw = cb[0] * x_lift + cb[1] * y_lift + cb[2];
        const float dyw = cb[4] * x_lift + cb[5] * y_lift + cb[6];
        const float dzw = cb[8] * x_lift + cb[9] * y_lift + cb[10];
        const float inv = 1.0f / sqrtf(dxw * dxw + dyw * dyw + dzw * dzw);
        const float dep = depth[(size_t)b * N + n];
        px[r] = cb[3]  + dep * dxw * inv;
        py[r] = cb[7]  + dep * dyw * inv;
        pz[r] = cb[11] + dep * dzw * inv;
        e[r]  = FLT_BIG;
    }

    const int Mc = M >> 5;                   // points per chunk (128)
    #pragma unroll 4
    for (int m = 0; m < Mc; m++) {
        const float4 q = s4[(m << 5) + chunk];
        #pragma unroll
        for (int r = 0; r < 8; r++) {
            float t = fmaf(-px[r], q.x, q.w);
            t = fmaf(-py[r], q.y, t);
            t = fmaf(-pz[r], q.z, t);
            e[r] = fminf(e[r], t);
        }
    }

    #pragma unroll
    for (int r = 0; r < 8; r++) {
        float v = e[r];
        v = fminf(v, __shfl_xor(v, 1));
        v = fminf(v, __shfl_xor(v, 2));
        v = fminf(v, __shfl_xor(v, 4));
        v = fminf(v, __shfl_xor(v, 8));
        v = fminf(v, __shfl_xor(v, 16));
        e[r] = v;
    }
    if (chunk == 0) {
        #pragma unroll
        for (int r = 0; r < 8; r++) {
            const int n = nbase + r;
            const float pn = px[r] * px[r] + py[r] * py[r] + pz[r] * pz[r];
            // clamp: true min dist^2 >= 0; makes float bits uint-monotone for kernel B
            d0[(size_t)b * N + n] = fmaxf(2.0f * e[r] + pn, 0.0f);
        }
    }
}

// Kernel B: exact sum of K smallest of N=4096 non-negative floats.
// 256 threads, 16 keys/thread in REGISTERS. 4-bit radix select, 8 rounds,
// predicated-add counting (no LDS atomics -> no same-bin serialization).
__global__ __launch_bounds__(256, 1) void select_mean_kernel(
    const float* __restrict__ d0,
    float* __restrict__ out,
    int N, int K)
{
    const int b    = blockIdx.x;
    const int tid  = threadIdx.x;
    const int lane = tid & 63;
    const int wv   = tid >> 6;

    __shared__ unsigned int wcnt[4 * 16];
    __shared__ unsigned int sel[2];          // [0]=nibble, [1]=remaining k
    __shared__ float  fpart[4];
    __shared__ unsigned int cpart[4];

    // Load 16 keys into registers (coalesced: t*256 + tid).
    unsigned int key[16];
    #pragma unroll
    for (int t = 0; t < 16; t++)
        key[t] = __float_as_uint(d0[(size_t)b * N + t * 256 + tid]);

    unsigned int k = (unsigned int)K;
    unsigned int prefix = 0u, mask = 0u;

    #pragma unroll
    for (int shift = 28; shift >= 0; shift -= 4) {
        unsigned int c[16];
        #pragma unroll
        for (int j2 = 0; j2 < 16; j2++) c[j2] = 0u;

        #pragma unroll
        for (int t = 0; t < 16; t++) {
            const unsigned int kk = key[t];
            const bool m = (kk & mask) == prefix;
            const unsigned int nib = (kk >> shift) & 15u;
            #pragma unroll
            for (int j2 = 0; j2 < 16; j2++)
                c[j2] += (unsigned int)(m && (nib == (unsigned int)j2));
        }

        // Wave-level reduce of the 16 counters.
        #pragma unroll
        for (int j2 = 0; j2 < 16; j2++) {
            unsigned int v = c[j2];
            v += __shfl_xor(v, 1);  v += __shfl_xor(v, 2);
            v += __shfl_xor(v, 4);  v += __shfl_xor(v, 8);
            v += __shfl_xor(v, 16); v += __shfl_xor(v, 32);
            c[j2] = v;
        }
        if (lane == 0) {
            #pragma unroll
            for (int j2 = 0; j2 < 16; j2++) wcnt[wv * 16 + j2] = c[j2];
        }
        __syncthreads();   // also protects sel[] from previous round's readers

        if (tid < 16) {
            unsigned int tot = wcnt[tid] + wcnt[16 + tid] + wcnt[32 + tid] + wcnt[48 + tid];
            unsigned int cum = tot;
            #pragma unroll
            for (int off = 1; off < 16; off <<= 1) {
                unsigned int u = __shfl_up(cum, off);
                if (tid >= off) cum += u;
            }
            const unsigned int cprev = cum - tot;
            if (cprev < k && k <= cum) { sel[0] = (unsigned int)tid; sel[1] = k - cprev; }
        }
        __syncthreads();

        prefix |= sel[0] << shift;
        k = sel[1];
        mask |= 15u << shift;
    }
    // prefix == float bits of the K-th smallest value T (keys are >= 0).

    const float tval = __uint_as_float(prefix);
    float sum = 0.0f;
    unsigned int cnt = 0u;
    #pragma unroll
    for (int t = 0; t < 16; t++) {
        if (key[t] < prefix) { sum += __uint_as_float(key[t]); cnt++; }
    }
    #pragma unroll
    for (int off = 32; off > 0; off >>= 1) {
        sum += __shfl_xor(sum, off);
        cnt += __shfl_xor(cnt, off);
    }
    if (lane == 0) { fpart[wv] = sum; cpart[wv] = cnt; }
    __syncthreads();
    if (tid == 0) {
        float s = fpart[0] + fpart[1] + fpart[2] + fpart[3];
        unsigned int c = cpart[0] + cpart[1] + cpart[2] + cpart[3];
        s += (float)(K - (int)c) * tval;    // ties / exact-Kth fill
        out[b] = 2.0f * s / (float)K;
    }
}

extern "C" void kernel_launch(void* const* d_in, const int* in_sizes, int n_in,
                              void* d_out, int out_size, void* d_ws, size_t ws_size,
                              hipStream_t stream)
{
    const float* c   = (const float*)d_in[0];
    const float* dep = (const float*)d_in[1];
    const float* pc  = (const float*)d_in[2];
    float* out = (float*)d_out;

    const int B = in_sizes[0] / 25;
    const int N = in_sizes[1] / B;     // 4096 (kernel B assumes 4096 = 16*256)
    const int M = in_sizes[2] / (3 * B);
    int R = 1; while (R * R < N) R++;

    float* d0 = (float*)d_ws;   // B*N floats of scratch

    dim3 gridA(N / 64, B);
    size_t ldsA = (size_t)M * sizeof(float4);
    hipLaunchKernelGGL(chamfer_min_kernel, gridA, dim3(256), ldsA, stream,
                       c, dep, pc, d0, N, M, R);

    const int K = ((N < M) ? N : M) / 2;
    hipLaunchKernelGGL(select_mean_kernel, dim3(B), dim3(256), 0, stream,
                       d0, out, N, K);
}